// Round 13
// baseline (173.569 us; speedup 1.0000x reference)
//
#include <hip/hip_runtime.h>
#include <hip/hip_bf16.h>

#define ALPHA 0.2f

typedef __attribute__((ext_vector_type(8))) short short8;
typedef __attribute__((ext_vector_type(8))) _Float16 h8;
typedef __attribute__((ext_vector_type(2))) _Float16 h2v;
typedef __attribute__((ext_vector_type(4))) float f32x4;

static constexpr int B = 4, N = 2048, F = 256, H = 8, D = 32;
static constexpr int SZ_X = B * N * F, SZ_ADJ = B * N * N, SZ_W = H * F * D, SZ_A = H * 2 * D;
static const float C1 = 1.4426950408889634f;           // log2(e)
static const float C2 = ALPHA * 1.4426950408889634f;

// ws layout (bytes):
// 0        WTbf bf16 [hd=256][f=256]  131072
// 131072   AF   f32  [H][64]          2048
// 133120   S1   f32  [32][2048]       262144
// 395264   UH   f16  [32][2048]       131072
// 526336   VH   f16  [32][2048]       131072
// 657408   WHT  f16  [b][hd=256][n=2048] 4194304   total ~4.85 MB

__device__ __forceinline__ unsigned rne16(unsigned u) {
    return u + 0x7fffu + ((u >> 16) & 1u);
}
__device__ __forceinline__ unsigned pk_rne(float a, float b) {   // bf16 pair
    return __builtin_amdgcn_perm(rne16(__float_as_uint(b)),
                                 rne16(__float_as_uint(a)), 0x07060302u);
}
__device__ __forceinline__ unsigned h2mul(unsigned a, unsigned b) {
    h2v r = __builtin_bit_cast(h2v, a) * __builtin_bit_cast(h2v, b);
    return __builtin_bit_cast(unsigned, r);
}
__device__ __forceinline__ unsigned h2max(unsigned a, unsigned b) {
    h2v r = __builtin_elementwise_max(__builtin_bit_cast(h2v, a),
                                      __builtin_bit_cast(h2v, b));
    return __builtin_bit_cast(unsigned, r);
}

// ---- k0: W[h][f][d] -> WTbf[hd][f] bf16; a -> AF --------------------------
__global__ void k0_prep(const float* __restrict__ Wp, const float* __restrict__ ap,
                        unsigned short* __restrict__ WTbf, float* __restrict__ AF) {
    int bid = blockIdx.x;              // 256 = H*D
    int h = bid >> 5, d = bid & 31;
    int f = threadIdx.x;
    WTbf[(h * D + d) * F + f] =
        (unsigned short)(rne16(__float_as_uint(Wp[(h * F + f) * D + d])) >> 16);
    if (d == 0 && f < 64) AF[h * 64 + f] = ap[h * 64 + f];
}

// ---- k12: LDS-tiled MFMA Wh + fused s1/s2/U/V epilogue (unchanged r12) ----
__global__ __launch_bounds__(256) void k12(const float* __restrict__ x,
                                           const unsigned short* __restrict__ WTbf,
                                           const float* __restrict__ AF,
                                           unsigned short* __restrict__ WHT,
                                           float* __restrict__ S1,
                                           _Float16* __restrict__ UH,
                                           _Float16* __restrict__ VH) {
    __shared__ unsigned short XA[16 * 264];   // [n][f] bf16, pad 264
    __shared__ unsigned short WB[256 * 40];   // [hd][32 f chunk] bf16, pad 40
    int bid = blockIdx.x;
    int b = bid >> 7;
    int n0 = (bid & 127) * 16;
    int t = threadIdx.x;
    int wave = t >> 6, lane = t & 63;
    int lm = lane & 15, lq = lane >> 4;

#pragma unroll
    for (int q = 0; q < 4; q++) {
        int idx = q * 256 + t;
        int row = idx >> 6, c16 = idx & 63;
        f32x4 v = *(const f32x4*)(x + (size_t)(b * N + n0 + row) * F + c16 * 4);
        unsigned* dst = (unsigned*)&XA[row * 264 + c16 * 4];
        dst[0] = pk_rne(v[0], v[1]);
        dst[1] = pk_rne(v[2], v[3]);
    }

    f32x4 acc[4] = {};
    for (int kc = 0; kc < 8; kc++) {
        __syncthreads();
#pragma unroll
        for (int q = 0; q < 4; q++) {
            int idx = q * 256 + t;
            int row = idx >> 2, c = idx & 3;
            short8 w = *(const short8*)(WTbf + row * 256 + kc * 32 + c * 8);
            *(short8*)&WB[row * 40 + c * 8] = w;
        }
        __syncthreads();
        short8 afr = *(const short8*)&XA[lm * 264 + kc * 32 + lq * 8];
#pragma unroll
        for (int c = 0; c < 4; c++) {
            short8 bfr = *(const short8*)&WB[(wave * 64 + c * 16 + lm) * 40 + lq * 8];
            acc[c] = __builtin_amdgcn_mfma_f32_16x16x32_bf16(afr, bfr, acc[c], 0, 0, 0);
        }
    }

#pragma unroll
    for (int c = 0; c < 4; c++) {
        int hd = wave * 64 + c * 16 + lm;
        unsigned short w0 = __builtin_bit_cast(unsigned short, (_Float16)acc[c][0]);
        unsigned short w1 = __builtin_bit_cast(unsigned short, (_Float16)acc[c][1]);
        unsigned short w2 = __builtin_bit_cast(unsigned short, (_Float16)acc[c][2]);
        unsigned short w3 = __builtin_bit_cast(unsigned short, (_Float16)acc[c][3]);
        uint2 pk;
        pk.x = (unsigned)w0 | ((unsigned)w1 << 16);
        pk.y = (unsigned)w2 | ((unsigned)w3 << 16);
        *(uint2*)&WHT[((size_t)b * 256 + hd) * 2048 + n0 + lq * 4] = pk;
    }
#pragma unroll
    for (int cp = 0; cp < 2; cp++) {
        int h = wave * 2 + cp;
        float a1l = AF[h * 64 + lm],      a1h = AF[h * 64 + 16 + lm];
        float a2l = AF[h * 64 + 32 + lm], a2h = AF[h * 64 + 48 + lm];
#pragma unroll
        for (int r = 0; r < 4; r++) {
            float s1p = acc[cp * 2][r] * a1l + acc[cp * 2 + 1][r] * a1h;
            float s2p = acc[cp * 2][r] * a2l + acc[cp * 2 + 1][r] * a2h;
#pragma unroll
            for (int off = 1; off <= 8; off <<= 1) {
                s1p += __shfl_xor(s1p, off);
                s2p += __shfl_xor(s2p, off);
            }
            if (lm == 0) {
                int bh = b * 8 + h, n = n0 + lq * 4 + r;
                S1[(size_t)bh * 2048 + n] = s1p;
                UH[(size_t)bh * 2048 + n] = (_Float16)exp2f(C1 * s2p);
                VH[(size_t)bh * 2048 + n] = (_Float16)exp2f(C2 * s2p);
            }
        }
    }
}

// ---- k3: barrier-free softmax+PV; per-wave LDS staging; adj fused ---------
// 512 blocks = (b, 16-i tile); 8 waves = 8 heads; ONE __syncthreads total.
__global__ __launch_bounds__(512) void k3_attn(
    const int* __restrict__ adj,
    const unsigned short* __restrict__ WHT,
    const float* __restrict__ S1,
    const _Float16* __restrict__ UH, const _Float16* __restrict__ VH,
    float* __restrict__ out) {
    __shared__ unsigned LM[16 * 66];              // [i][j-word], stride 66: 2-way free
    __shared__ unsigned short LW[8 * 32 * 136];   // per-wave [32 d][128 j], pad 136

    int bid = blockIdx.x;                         // 512 = b*128 + it
    int b = bid >> 7;
    int i0 = (bid & 127) * 16;
    int t = threadIdx.x;
    int wave = t >> 6, lane = t & 63;
    int h = wave;
    int bh = b * 8 + h;
    int irow = lane & 15, quad = lane >> 4;

    // ---- fused adj -> LM bitmask: wave stages 2 i-rows via ballot ---------
#pragma unroll
    for (int rr = 0; rr < 2; rr++) {
        int row = wave * 2 + rr;
        const int* arow = adj + ((size_t)(b * N + i0 + row)) * N;
#pragma unroll 4
        for (int w64 = 0; w64 < 32; w64++) {
            int v = arow[w64 * 64 + lane];                 // coalesced, adj read ONCE
            unsigned long long m = __ballot(v != 0);       // bit L <-> j = w64*64+L
            if (lane == 0) {
                LM[row * 66 + w64 * 2]     = (unsigned)m;
                LM[row * 66 + w64 * 2 + 1] = (unsigned)(m >> 32);
            }
        }
    }
    __syncthreads();                                       // the ONLY barrier

    float s1i = S1[(size_t)bh * N + i0 + irow];
    unsigned short cw = __builtin_bit_cast(unsigned short, (_Float16)exp2f((C2 - C1) * s1i));
    unsigned ci2 = (unsigned)cw | ((unsigned)cw << 16);

    union { h8 v; unsigned u[4]; } ones;
    ones.u[0] = ones.u[1] = ones.u[2] = ones.u[3] = 0x3C003C00u;

    unsigned short* lw = LW + wave * (32 * 136);           // private region
    const unsigned short* wsrc = WHT + ((size_t)b * 256 + h * 32) * 2048;
    const _Float16* up = UH + (size_t)bh * 2048;
    const _Float16* vp = VH + (size_t)bh * 2048;

    f32x4 acc0 = {0.f, 0.f, 0.f, 0.f};
    f32x4 acc1 = {0.f, 0.f, 0.f, 0.f};
    f32x4 accL = {0.f, 0.f, 0.f, 0.f};

    for (int cc = 0; cc < 16; cc++) {
        // stage own 32 rows x 128 j (8 KB), no barrier: intra-wave lgkmcnt only
#pragma unroll
        for (int k = 0; k < 8; k++) {
            int unit = k * 64 + lane;
            int row = unit >> 4, u16 = unit & 15;
            short8 v = *(const short8*)(wsrc + (size_t)row * 2048 + cc * 128 + u16 * 8);
            *(short8*)&lw[row * 136 + u16 * 8] = v;
        }
#pragma unroll
        for (int g = 0; g < 4; g++) {
            unsigned mk = LM[irow * 66 + cc * 4 + g] >> (quad * 8);
            int jl = g * 32 + quad * 8;
            uint4 uw = *(const uint4*)(up + cc * 128 + jl);   // quad-broadcast, L1
            uint4 vw = *(const uint4*)(vp + cc * 128 + jl);
            unsigned m0 = ((mk & 1u)   ? 0x3C00u : 0u) | ((mk & 2u)   ? 0x3C000000u : 0u);
            unsigned m1 = ((mk & 4u)   ? 0x3C00u : 0u) | ((mk & 8u)   ? 0x3C000000u : 0u);
            unsigned m2 = ((mk & 16u)  ? 0x3C00u : 0u) | ((mk & 32u)  ? 0x3C000000u : 0u);
            unsigned m3 = ((mk & 64u)  ? 0x3C00u : 0u) | ((mk & 128u) ? 0x3C000000u : 0u);
            union { h8 v; unsigned u[4]; } af;
            af.u[0] = h2mul(h2max(uw.x, h2mul(ci2, vw.x)), m0);
            af.u[1] = h2mul(h2max(uw.y, h2mul(ci2, vw.y)), m1);
            af.u[2] = h2mul(h2max(uw.z, h2mul(ci2, vw.z)), m2);
            af.u[3] = h2mul(h2max(uw.w, h2mul(ci2, vw.w)), m3);
            h8 bf0 = *(const h8*)&lw[irow * 136 + jl];
            h8 bf1 = *(const h8*)&lw[(16 + irow) * 136 + jl];
            acc0 = __builtin_amdgcn_mfma_f32_16x16x32_f16(af.v, bf0, acc0, 0, 0, 0);
            acc1 = __builtin_amdgcn_mfma_f32_16x16x32_f16(af.v, bf1, acc1, 0, 0, 0);
            accL = __builtin_amdgcn_mfma_f32_16x16x32_f16(af.v, ones.v, accL, 0, 0, 0);
        }
    }
#pragma unroll
    for (int r = 0; r < 4; r++) {
        float lr = accL[r];
        float rin = 1.0f / (lr > 0.f ? lr : 1.f);
        float v0 = acc0[r] * rin;
        float v1 = acc1[r] * rin;
        v0 = v0 > 0.f ? v0 : __expf(v0) - 1.f;     // ELU
        v1 = v1 > 0.f ? v1 : __expf(v1) - 1.f;
        size_t rowb = (size_t)(b * N + i0 + quad * 4 + r) * (H * D) + h * D;
        out[rowb + irow] = v0;
        out[rowb + 16 + irow] = v1;
    }
}

extern "C" void kernel_launch(void* const* d_in, const int* in_sizes, int n_in,
                              void* d_out, int out_size, void* d_ws, size_t ws_size,
                              hipStream_t stream) {
    const void *xP = nullptr, *adjP = nullptr, *WP = nullptr, *aP = nullptr;
    for (int i = 0; i < n_in; i++) {
        switch (in_sizes[i]) {
            case SZ_X:   xP = d_in[i]; break;
            case SZ_ADJ: adjP = d_in[i]; break;
            case SZ_W:   WP = d_in[i]; break;
            case SZ_A:   aP = d_in[i]; break;
            default: break;
        }
    }
    if (!xP || !adjP || !WP || !aP) { xP = d_in[0]; adjP = d_in[1]; WP = d_in[2]; aP = d_in[3]; }
    float* out = (float*)d_out;

    char* ws = (char*)d_ws;
    unsigned short* WTbf = (unsigned short*)(ws);
    float* AF  = (float*)(ws + 131072);
    float* S1  = (float*)(ws + 133120);
    _Float16* UH = (_Float16*)(ws + 395264);
    _Float16* VH = (_Float16*)(ws + 526336);
    unsigned short* WHT = (unsigned short*)(ws + 657408);

    k0_prep<<<256, 256, 0, stream>>>((const float*)WP, (const float*)aP, WTbf, AF);
    k12<<<512, 256, 0, stream>>>((const float*)xP, WTbf, AF, WHT, S1, UH, VH);
    k3_attn<<<512, 512, 0, stream>>>((const int*)adjP, WHT, S1, UH, VH, out);
}

// Round 14
// 157.625 us; speedup vs baseline: 1.1012x; 1.1012x over previous
//
#include <hip/hip_runtime.h>
#include <hip/hip_bf16.h>

#define ALPHA 0.2f

typedef __attribute__((ext_vector_type(8))) short short8;
typedef __attribute__((ext_vector_type(4))) short s4;
typedef __attribute__((ext_vector_type(8))) _Float16 h8;
typedef __attribute__((ext_vector_type(2))) _Float16 h2v;
typedef __attribute__((ext_vector_type(4))) float f32x4;

static constexpr int B = 4, N = 2048, F = 256, H = 8, D = 32;
static constexpr int SZ_X = B * N * F, SZ_ADJ = B * N * N, SZ_W = H * F * D, SZ_A = H * 2 * D;
static const float C1 = 1.4426950408889634f;           // log2(e)
static const float C2 = ALPHA * 1.4426950408889634f;

// ws layout (bytes):
// 0        WT2  bf16 [kc=8][hd=256][32] 131072   (B-frag-contiguous W)
// 131072   AF   f32  [H][64]            2048
// 133120   S1   f32  [32][2048]         262144
// 395264   UH   f16  [32][2048]         131072
// 526336   VH   f16  [32][2048]         131072
// 657408   WHT  f16  [b][hd=256][2048]  4194304
// 4851712  BM   u64  [B*N*N/64]         2097152   total ~6.6 MB

__device__ __forceinline__ unsigned rne16(unsigned u) {
    return u + 0x7fffu + ((u >> 16) & 1u);
}
__device__ __forceinline__ unsigned pk_rne(float a, float b) {   // bf16 pair
    return __builtin_amdgcn_perm(rne16(__float_as_uint(b)),
                                 rne16(__float_as_uint(a)), 0x07060302u);
}
__device__ __forceinline__ unsigned h2mul(unsigned a, unsigned b) {
    h2v r = __builtin_bit_cast(h2v, a) * __builtin_bit_cast(h2v, b);
    return __builtin_bit_cast(unsigned, r);
}
__device__ __forceinline__ unsigned h2max(unsigned a, unsigned b) {
    h2v r = __builtin_elementwise_max(__builtin_bit_cast(h2v, a),
                                      __builtin_bit_cast(h2v, b));
    return __builtin_bit_cast(unsigned, r);
}
__device__ __forceinline__ unsigned dup16f(float x) {
    unsigned short w = __builtin_bit_cast(unsigned short, (_Float16)x);
    return (unsigned)w | ((unsigned)w << 16);
}

// ---- k0: W[h][f][d] -> WT2[f>>5][h*32+d][f&31] bf16; a -> AF --------------
__global__ void k0_prep(const float* __restrict__ Wp, const float* __restrict__ ap,
                        unsigned short* __restrict__ WT2, float* __restrict__ AF) {
    int bid = blockIdx.x;              // 256 = H*D
    int h = bid >> 5, d = bid & 31;
    int f = threadIdx.x;
    unsigned short v = (unsigned short)(rne16(__float_as_uint(Wp[(h * F + f) * D + d])) >> 16);
    WT2[(size_t)(f >> 5) * 8192 + (h * 32 + d) * 32 + (f & 31)] = v;
    if (d == 0 && f < 64) AF[h * 64 + f] = ap[h * 64 + f];
}

// ---- kbit: adj -> u64 bitmask via ballot (coalesced stream) ---------------
__global__ void kbit(const int* __restrict__ adj, unsigned long long* __restrict__ bm) {
    int wid = blockIdx.x * 4 + (threadIdx.x >> 6);   // 4096 blocks
    int lane = threadIdx.x & 63;
    size_t base = (size_t)wid * 16;
#pragma unroll
    for (int s = 0; s < 16; s++) {
        size_t strip = base + s;
        int v = adj[strip * 64 + lane];
        unsigned long long m = __ballot(v != 0);
        if (lane == 0) bm[strip] = m;
    }
}

// ---- k12: Wh MFMA with direct coalesced WT2 B-frags; 1 barrier ------------
__global__ __launch_bounds__(256) void k12(const float* __restrict__ x,
                                           const unsigned short* __restrict__ WT2,
                                           const float* __restrict__ AF,
                                           unsigned short* __restrict__ WHT,
                                           float* __restrict__ S1,
                                           _Float16* __restrict__ UH,
                                           _Float16* __restrict__ VH) {
    __shared__ unsigned short XA[16 * 264];   // [n][f] bf16, stride 264 (528B, /16 ok)
    int bid = blockIdx.x;                     // 512 = b*128 + ntile
    int b = bid >> 7;
    int n0 = (bid & 127) * 16;
    int t = threadIdx.x;
    int wave = t >> 6, lane = t & 63;
    int lm = lane & 15, lq = lane >> 4;

    // stage XA coalesced: x fp32 -> bf16
#pragma unroll
    for (int q = 0; q < 4; q++) {
        int idx = q * 256 + t;
        int row = idx >> 6, c16 = idx & 63;
        f32x4 v = *(const f32x4*)(x + (size_t)(b * N + n0 + row) * F + c16 * 4);
        unsigned* dst = (unsigned*)&XA[row * 264 + c16 * 4];
        dst[0] = pk_rne(v[0], v[1]);
        dst[1] = pk_rne(v[2], v[3]);
    }
    __syncthreads();

    f32x4 acc[4] = {};
#pragma unroll
    for (int kc = 0; kc < 8; kc++) {
        short8 afr = *(const short8*)&XA[lm * 264 + kc * 32 + lq * 8];
#pragma unroll
        for (int c = 0; c < 4; c++) {
            int hd = wave * 64 + c * 16 + lm;
            // fully-contiguous 1KB wave-load, L2-resident
            short8 bfr = *(const short8*)(WT2 + (size_t)kc * 8192 + hd * 32 + lq * 8);
            acc[c] = __builtin_amdgcn_mfma_f32_16x16x32_bf16(afr, bfr, acc[c], 0, 0, 0);
        }
    }

    // epilogue 1: WHT[b][hd][n] f16, 8B packed stores
#pragma unroll
    for (int c = 0; c < 4; c++) {
        int hd = wave * 64 + c * 16 + lm;
        unsigned short w0 = __builtin_bit_cast(unsigned short, (_Float16)acc[c][0]);
        unsigned short w1 = __builtin_bit_cast(unsigned short, (_Float16)acc[c][1]);
        unsigned short w2 = __builtin_bit_cast(unsigned short, (_Float16)acc[c][2]);
        unsigned short w3 = __builtin_bit_cast(unsigned short, (_Float16)acc[c][3]);
        uint2 pk;
        pk.x = (unsigned)w0 | ((unsigned)w1 << 16);
        pk.y = (unsigned)w2 | ((unsigned)w3 << 16);
        *(uint2*)&WHT[((size_t)b * 256 + hd) * 2048 + n0 + lq * 4] = pk;
    }
    // epilogue 2: s1/s2 -> S1/UH/VH
#pragma unroll
    for (int cp = 0; cp < 2; cp++) {
        int h = wave * 2 + cp;
        float a1l = AF[h * 64 + lm],      a1h = AF[h * 64 + 16 + lm];
        float a2l = AF[h * 64 + 32 + lm], a2h = AF[h * 64 + 48 + lm];
#pragma unroll
        for (int r = 0; r < 4; r++) {
            float s1p = acc[cp * 2][r] * a1l + acc[cp * 2 + 1][r] * a1h;
            float s2p = acc[cp * 2][r] * a2l + acc[cp * 2 + 1][r] * a2h;
#pragma unroll
            for (int off = 1; off <= 8; off <<= 1) {
                s1p += __shfl_xor(s1p, off);
                s2p += __shfl_xor(s2p, off);
            }
            if (lm == 0) {
                int bh = b * 8 + h, n = n0 + lq * 4 + r;
                S1[(size_t)bh * 2048 + n] = s1p;
                UH[(size_t)bh * 2048 + n] = (_Float16)exp2f(C1 * s2p);
                VH[(size_t)bh * 2048 + n] = (_Float16)exp2f(C2 * s2p);
            }
        }
    }
}

// ---- k3: block=(b,h,128-i tile); shared dbuf WHT staging; 2 m-frags/wave --
__global__ __launch_bounds__(256) void k3_attn(
    const unsigned* __restrict__ bm32,
    const unsigned short* __restrict__ WHT,
    const float* __restrict__ S1,
    const _Float16* __restrict__ UH, const _Float16* __restrict__ VH,
    float* __restrict__ out) {
    __shared__ unsigned LM[4][32 * 66];            // per-wave 32-row bitmask
    __shared__ unsigned short LW[2][32 * 140];     // dbuf [d][128j], stride 140 (b64 ~2-way)

    int bid = blockIdx.x;                          // 512 = (b*8+h)*16 + isup
    int isup = bid & 15;
    int bh = bid >> 4;
    int b = bh >> 3, h = bh & 7;
    int i0 = isup * 128;
    int t = threadIdx.x;
    int wave = t >> 6, lane = t & 63;
    int irow = lane & 15, quad = lane >> 4;
    int iw = i0 + wave * 32;                       // this wave's 32 i-rows

    // per-wave private bitmask staging (no barrier needed)
    {
        unsigned* lm = LM[wave];
        const unsigned* src = bm32 + ((size_t)(b * N + iw)) * 64;
#pragma unroll 4
        for (int r = 0; r < 32; r++)
            lm[r * 66 + lane] = src[(size_t)r * 64 + lane];
    }

    const unsigned short* wsrc = WHT + ((size_t)b * 256 + h * 32) * 2048;
    int srow = t >> 3, sseg = (t & 7) * 16;        // staging map: 32B/thread

    // prologue: stage chunk 0
    {
        const unsigned short* g = wsrc + (size_t)srow * 2048 + sseg;
        union { short8 v; s4 q[2]; } a, c;
        a.v = *(const short8*)(g);
        c.v = *(const short8*)(g + 8);
        unsigned short* d = &LW[0][srow * 140 + sseg];
        *(s4*)(d) = a.q[0]; *(s4*)(d + 4) = a.q[1];
        *(s4*)(d + 8) = c.q[0]; *(s4*)(d + 12) = c.q[1];
    }

    float s1A = S1[(size_t)bh * 2048 + iw + irow];
    float s1B = S1[(size_t)bh * 2048 + iw + 16 + irow];
    unsigned ci2A = dup16f(exp2f((C2 - C1) * s1A));
    unsigned ci2B = dup16f(exp2f((C2 - C1) * s1B));
    const _Float16* up = UH + (size_t)bh * 2048;
    const _Float16* vp = VH + (size_t)bh * 2048;

    union { h8 v; unsigned u[4]; } ones;
    ones.u[0] = ones.u[1] = ones.u[2] = ones.u[3] = 0x3C003C00u;

    f32x4 aA0 = {0,0,0,0}, aA1 = {0,0,0,0}, aAL = {0,0,0,0};
    f32x4 aB0 = {0,0,0,0}, aB1 = {0,0,0,0}, aBL = {0,0,0,0};
    __syncthreads();

    for (int cc = 0; cc < 16; cc++) {
        // prefetch chunk cc+1 into registers (overlaps compute)
        union { short8 v; s4 q[2]; } pa, pc;
        if (cc < 15) {
            const unsigned short* g = wsrc + (size_t)srow * 2048 + (cc + 1) * 128 + sseg;
            pa.v = *(const short8*)(g);
            pc.v = *(const short8*)(g + 8);
        }
        const unsigned short* lwp = LW[cc & 1];
        const unsigned* lmw = LM[wave];
#pragma unroll
        for (int ks = 0; ks < 4; ks++) {
            int jl = ks * 32 + quad * 8;
            int jg = cc * 128 + jl;
            uint4 uw = *(const uint4*)(up + jg);
            uint4 vw = *(const uint4*)(vp + jg);
            unsigned mkA = lmw[irow * 66 + cc * 4 + ks] >> (quad * 8);
            unsigned mkB = lmw[(16 + irow) * 66 + cc * 4 + ks] >> (quad * 8);
            unsigned mA0 = ((mkA & 1u)  ? 0x3C00u : 0u) | ((mkA & 2u)   ? 0x3C000000u : 0u);
            unsigned mA1 = ((mkA & 4u)  ? 0x3C00u : 0u) | ((mkA & 8u)   ? 0x3C000000u : 0u);
            unsigned mA2 = ((mkA & 16u) ? 0x3C00u : 0u) | ((mkA & 32u)  ? 0x3C000000u : 0u);
            unsigned mA3 = ((mkA & 64u) ? 0x3C00u : 0u) | ((mkA & 128u) ? 0x3C000000u : 0u);
            unsigned mB0 = ((mkB & 1u)  ? 0x3C00u : 0u) | ((mkB & 2u)   ? 0x3C000000u : 0u);
            unsigned mB1 = ((mkB & 4u)  ? 0x3C00u : 0u) | ((mkB & 8u)   ? 0x3C000000u : 0u);
            unsigned mB2 = ((mkB & 16u) ? 0x3C00u : 0u) | ((mkB & 32u)  ? 0x3C000000u : 0u);
            unsigned mB3 = ((mkB & 64u) ? 0x3C00u : 0u) | ((mkB & 128u) ? 0x3C000000u : 0u);
            union { h8 v; unsigned u[4]; } afA, afB;
            afA.u[0] = h2mul(h2max(uw.x, h2mul(ci2A, vw.x)), mA0);
            afA.u[1] = h2mul(h2max(uw.y, h2mul(ci2A, vw.y)), mA1);
            afA.u[2] = h2mul(h2max(uw.z, h2mul(ci2A, vw.z)), mA2);
            afA.u[3] = h2mul(h2max(uw.w, h2mul(ci2A, vw.w)), mA3);
            afB.u[0] = h2mul(h2max(uw.x, h2mul(ci2B, vw.x)), mB0);
            afB.u[1] = h2mul(h2max(uw.y, h2mul(ci2B, vw.y)), mB1);
            afB.u[2] = h2mul(h2max(uw.z, h2mul(ci2B, vw.z)), mB2);
            afB.u[3] = h2mul(h2max(uw.w, h2mul(ci2B, vw.w)), mB3);
            union { short8 v; s4 q[2]; } bf0, bf1;
            bf0.q[0] = *(const s4*)&lwp[irow * 140 + jl];
            bf0.q[1] = *(const s4*)&lwp[irow * 140 + jl + 4];
            bf1.q[0] = *(const s4*)&lwp[(16 + irow) * 140 + jl];
            bf1.q[1] = *(const s4*)&lwp[(16 + irow) * 140 + jl + 4];
            h8 b0 = __builtin_bit_cast(h8, bf0.v);
            h8 b1 = __builtin_bit_cast(h8, bf1.v);
            aA0 = __builtin_amdgcn_mfma_f32_16x16x32_f16(afA.v, b0, aA0, 0, 0, 0);
            aA1 = __builtin_amdgcn_mfma_f32_16x16x32_f16(afA.v, b1, aA1, 0, 0, 0);
            aAL = __builtin_amdgcn_mfma_f32_16x16x32_f16(afA.v, ones.v, aAL, 0, 0, 0);
            aB0 = __builtin_amdgcn_mfma_f32_16x16x32_f16(afB.v, b0, aB0, 0, 0, 0);
            aB1 = __builtin_amdgcn_mfma_f32_16x16x32_f16(afB.v, b1, aB1, 0, 0, 0);
            aBL = __builtin_amdgcn_mfma_f32_16x16x32_f16(afB.v, ones.v, aBL, 0, 0, 0);
        }
        if (cc < 15) {
            unsigned short* d = &LW[(cc + 1) & 1][srow * 140 + sseg];
            *(s4*)(d) = pa.q[0]; *(s4*)(d + 4) = pa.q[1];
            *(s4*)(d + 8) = pc.q[0]; *(s4*)(d + 12) = pc.q[1];
        }
        __syncthreads();
    }

#pragma unroll
    for (int r = 0; r < 4; r++) {
        float lA = aAL[r], lB = aBL[r];
        float rA = 1.0f / (lA > 0.f ? lA : 1.f);
        float rB = 1.0f / (lB > 0.f ? lB : 1.f);
        float vA0 = aA0[r] * rA, vA1 = aA1[r] * rA;
        float vB0 = aB0[r] * rB, vB1 = aB1[r] * rB;
        vA0 = vA0 > 0.f ? vA0 : __expf(vA0) - 1.f;   // ELU
        vA1 = vA1 > 0.f ? vA1 : __expf(vA1) - 1.f;
        vB0 = vB0 > 0.f ? vB0 : __expf(vB0) - 1.f;
        vB1 = vB1 > 0.f ? vB1 : __expf(vB1) - 1.f;
        int iA = iw + quad * 4 + r, iB = iA + 16;
        size_t rbA = (size_t)(b * N + iA) * 256 + h * 32;
        size_t rbB = (size_t)(b * N + iB) * 256 + h * 32;
        out[rbA + irow] = vA0;
        out[rbA + 16 + irow] = vA1;
        out[rbB + irow] = vB0;
        out[rbB + 16 + irow] = vB1;
    }
}

extern "C" void kernel_launch(void* const* d_in, const int* in_sizes, int n_in,
                              void* d_out, int out_size, void* d_ws, size_t ws_size,
                              hipStream_t stream) {
    const void *xP = nullptr, *adjP = nullptr, *WP = nullptr, *aP = nullptr;
    for (int i = 0; i < n_in; i++) {
        switch (in_sizes[i]) {
            case SZ_X:   xP = d_in[i]; break;
            case SZ_ADJ: adjP = d_in[i]; break;
            case SZ_W:   WP = d_in[i]; break;
            case SZ_A:   aP = d_in[i]; break;
            default: break;
        }
    }
    if (!xP || !adjP || !WP || !aP) { xP = d_in[0]; adjP = d_in[1]; WP = d_in[2]; aP = d_in[3]; }
    float* out = (float*)d_out;

    char* ws = (char*)d_ws;
    unsigned short* WT2 = (unsigned short*)(ws);
    float* AF  = (float*)(ws + 131072);
    float* S1  = (float*)(ws + 133120);
    _Float16* UH = (_Float16*)(ws + 395264);
    _Float16* VH = (_Float16*)(ws + 526336);
    unsigned short* WHT = (unsigned short*)(ws + 657408);
    unsigned long long* BM = (unsigned long long*)(ws + 4851712);

    k0_prep<<<256, 256, 0, stream>>>((const float*)WP, (const float*)aP, WT2, AF);
    kbit<<<4096, 256, 0, stream>>>((const int*)adjP, BM);
    k12<<<512, 256, 0, stream>>>((const float*)xP, WT2, AF, WHT, S1, UH, VH);
    k3_attn<<<512, 256, 0, stream>>>((const unsigned*)BM, WHT, S1, UH, VH, out);
}